// Round 1
// baseline (338.322 us; speedup 1.0000x reference)
//
#include <hip/hip_runtime.h>
#include <hip/hip_bf16.h>

#define NN 50000
#define EE 800000
#define IN_F 128
#define HC 64
#define NEG_SLOPE 0.2f
#define BN_EPS 1e-5f

// ---------------- Kernel 1: h = x@W, res = x@W_res, al_s, al_d ----------------
// block = 256 threads, 16 rows/block. thread -> (row r = tid>>4, channels c4 = (tid&15)*4 .. +3)
__global__ __launch_bounds__(256) void gemm_al_kernel(
    const float* __restrict__ x, const float* __restrict__ W, const float* __restrict__ Wres,
    const float* __restrict__ a_src, const float* __restrict__ a_dst,
    float* __restrict__ h, float* __restrict__ res,
    float* __restrict__ al_s, float* __restrict__ al_d) {
  __shared__ float W_lds[IN_F * HC];    // 32KB, layout [k][c]
  __shared__ float Wr_lds[IN_F * HC];   // 32KB
  __shared__ float x_lds[16 * 132];     // 16 rows, stride 132 (bank-conflict-free broadcast)

  const int tid = threadIdx.x;
  // stage W, W_res (linear copy, coalesced float4)
  for (int i = tid; i < IN_F * HC / 4; i += 256) {
    ((float4*)W_lds)[i]  = ((const float4*)W)[i];
    ((float4*)Wr_lds)[i] = ((const float4*)Wres)[i];
  }
  const int r0 = blockIdx.x * 16;
  // stage 16 x-rows (128 floats each)
  for (int i = tid; i < 512; i += 256) {
    int row = i >> 5;       // 32 float4 per row
    int kk = i & 31;
    *(float4*)&x_lds[row * 132 + kk * 4] = ((const float4*)(x + (size_t)r0 * IN_F))[i];
  }
  __syncthreads();

  const int r = tid >> 4;            // 0..15
  const int c4 = (tid & 15) * 4;     // 0,4,...,60
  float4 acc1 = make_float4(0.f, 0.f, 0.f, 0.f);
  float4 acc2 = make_float4(0.f, 0.f, 0.f, 0.f);
#pragma unroll 8
  for (int k = 0; k < IN_F; ++k) {
    float xv = x_lds[r * 132 + k];
    float4 w  = *(const float4*)&W_lds[k * HC + c4];
    float4 wr = *(const float4*)&Wr_lds[k * HC + c4];
    acc1.x = fmaf(xv, w.x, acc1.x);
    acc1.y = fmaf(xv, w.y, acc1.y);
    acc1.z = fmaf(xv, w.z, acc1.z);
    acc1.w = fmaf(xv, w.w, acc1.w);
    acc2.x = fmaf(xv, wr.x, acc2.x);
    acc2.y = fmaf(xv, wr.y, acc2.y);
    acc2.z = fmaf(xv, wr.z, acc2.z);
    acc2.w = fmaf(xv, wr.w, acc2.w);
  }
  const int node = r0 + r;
  *(float4*)&h[(size_t)node * HC + c4]   = acc1;
  *(float4*)&res[(size_t)node * HC + c4] = acc2;

  // attention logits: al_s[n,head] = sum_c h[n,head,c]*a_src[head,c]
  const int head = (tid & 15) >> 2;          // c4 >> 4
  const int coff = c4 & 15;                  // 0,4,8,12 within head
  float4 as4 = *(const float4*)&a_src[head * 16 + coff];
  float4 ad4 = *(const float4*)&a_dst[head * 16 + coff];
  float als = acc1.x * as4.x + acc1.y * as4.y + acc1.z * as4.z + acc1.w * as4.w;
  float ald = acc1.x * ad4.x + acc1.y * ad4.y + acc1.z * ad4.z + acc1.w * ad4.w;
  als += __shfl_xor(als, 1); als += __shfl_xor(als, 2);
  ald += __shfl_xor(ald, 1); ald += __shfl_xor(ald, 2);
  if ((tid & 3) == 0) {
    al_s[node * 4 + head] = als;
    al_d[node * 4 + head] = ald;
  }
}

// ---------------- Kernel 2: histogram of dst ----------------
__global__ __launch_bounds__(256) void hist_kernel(const int* __restrict__ dst,
                                                   int* __restrict__ counts) {
  int e = blockIdx.x * 256 + threadIdx.x;
  if (e < EE) atomicAdd(&counts[dst[e]], 1);
}

// ---------------- Kernel 3: exclusive scan -> row_ptr, cursor ----------------
__global__ __launch_bounds__(1024) void scan_kernel(const int* __restrict__ counts,
                                                    int* __restrict__ row_ptr,
                                                    int* __restrict__ cursor) {
  __shared__ int sdata[1024];
  __shared__ int s_carry;
  const int tid = threadIdx.x;
  if (tid == 0) s_carry = 0;
  __syncthreads();
  for (int base = 0; base < NN; base += 1024) {
    int i = base + tid;
    int v = (i < NN) ? counts[i] : 0;
    sdata[tid] = v;
    __syncthreads();
    for (int off = 1; off < 1024; off <<= 1) {
      int t = (tid >= off) ? sdata[tid - off] : 0;
      __syncthreads();
      sdata[tid] += t;
      __syncthreads();
    }
    int incl = sdata[tid];
    int carry = s_carry;
    if (i < NN) {
      int e = carry + incl - v;
      row_ptr[i] = e;
      cursor[i] = e;
    }
    __syncthreads();
    if (tid == 0) s_carry = carry + sdata[1023];
    __syncthreads();
  }
  if (tid == 0) row_ptr[NN] = s_carry;
}

// ---------------- Kernel 4: scatter edges into CSR ----------------
__global__ __launch_bounds__(256) void scatter_kernel(const int* __restrict__ src,
                                                      const int* __restrict__ dst,
                                                      int* __restrict__ cursor,
                                                      int* __restrict__ col) {
  int e = blockIdx.x * 256 + threadIdx.x;
  if (e < EE) {
    int d = dst[e];
    int p = atomicAdd(&cursor[d], 1);
    col[p] = src[e];
  }
}

// ---------------- Kernel 5: per-node attention aggregate (wave per node) ----------------
__global__ __launch_bounds__(256) void node_kernel(
    const float* __restrict__ h, const float* __restrict__ al_s, const float* __restrict__ al_d,
    const int* __restrict__ row_ptr, const int* __restrict__ col,
    float* __restrict__ out_pre) {
  const int node = blockIdx.x * 4 + (threadIdx.x >> 6);
  const int lane = threadIdx.x & 63;
  const int head = lane >> 4;

  const float ald = al_d[node * 4 + head];
  // self loop (GATConv adds them for every node)
  float e0 = al_s[node * 4 + head] + ald;
  e0 = e0 > 0.f ? e0 : NEG_SLOPE * e0;
  float m = __expf(e0);
  float denom = m;
  float acc = m * h[(size_t)node * HC + lane];

  const int beg = row_ptr[node];
  const int end = row_ptr[node + 1];
  for (int idx = beg; idx < end; ++idx) {
    int s = col[idx];
    float as = al_s[s * 4 + head];
    float ee = as + ald;
    ee = ee > 0.f ? ee : NEG_SLOPE * ee;
    float mm = __expf(ee);
    denom += mm;
    acc = fmaf(mm, h[(size_t)s * HC + lane], acc);
  }
  out_pre[(size_t)node * HC + lane] = acc / denom;
}

// ---------------- Kernel 6: BN statistics (sum, sumsq per channel) ----------------
__global__ __launch_bounds__(256) void stats_kernel(const float* __restrict__ out_pre,
                                                    float* __restrict__ sums) {
  const int c = threadIdx.x & 63;
  const int rg = threadIdx.x >> 6;   // 0..3
  float s = 0.f, s2 = 0.f;
  for (int r = blockIdx.x * 4 + rg; r < NN; r += gridDim.x * 4) {
    float v = out_pre[(size_t)r * HC + c];
    s += v;
    s2 = fmaf(v, v, s2);
  }
  __shared__ float lds[512];
  lds[threadIdx.x] = s;
  lds[256 + threadIdx.x] = s2;
  __syncthreads();
  if (threadIdx.x < 64) {
    float ts = lds[c] + lds[64 + c] + lds[128 + c] + lds[192 + c];
    float t2 = lds[256 + c] + lds[256 + 64 + c] + lds[256 + 128 + c] + lds[256 + 192 + c];
    atomicAdd(&sums[c], ts);
    atomicAdd(&sums[64 + c], t2);
  }
}

// ---------------- Kernel 7: BN + ELU + residual ----------------
__global__ __launch_bounds__(256) void final_kernel(
    const float* __restrict__ out_pre, const float* __restrict__ res,
    const float* __restrict__ sums, const float* __restrict__ gamma,
    const float* __restrict__ beta, float* __restrict__ out) {
  const int i = blockIdx.x * 256 + threadIdx.x;   // 12500*256 == NN*HC exactly
  const int c = i & 63;
  const float inv_n = 1.0f / (float)NN;
  float mu = sums[c] * inv_n;
  float var = sums[64 + c] * inv_n - mu * mu;
  float rinv = rsqrtf(var + BN_EPS);
  float v = (out_pre[i] - mu) * rinv * gamma[c] + beta[c];
  v = v > 0.f ? v : (__expf(v) - 1.0f);
  out[i] = v + res[i];
}

extern "C" void kernel_launch(void* const* d_in, const int* in_sizes, int n_in,
                              void* d_out, int out_size, void* d_ws, size_t ws_size,
                              hipStream_t stream) {
  const float* x     = (const float*)d_in[0];
  const int*   ei    = (const int*)d_in[1];     // [2,E]: src = ei, dst = ei+E
  const float* W     = (const float*)d_in[2];
  const float* a_src = (const float*)d_in[3];
  const float* a_dst = (const float*)d_in[4];
  // d_in[5] = bias: cancels exactly through BatchNorm mean-subtraction -> unused
  const float* gamma = (const float*)d_in[6];
  const float* beta  = (const float*)d_in[7];
  const float* Wres  = (const float*)d_in[8];
  float* out = (float*)d_out;

  char* ws = (char*)d_ws;
  float* h       = (float*)ws; ws += (size_t)NN * HC * 4;
  float* resb    = (float*)ws; ws += (size_t)NN * HC * 4;
  float* out_pre = (float*)ws; ws += (size_t)NN * HC * 4;
  float* al_s    = (float*)ws; ws += (size_t)NN * 4 * 4;
  float* al_d    = (float*)ws; ws += (size_t)NN * 4 * 4;
  float* sums    = (float*)ws; ws += 128 * 4;          // [0:64]=sum, [64:128]=sumsq
  int*   counts  = (int*)ws;   ws += (size_t)NN * 4;   // contiguous with sums for one memset
  int*   row_ptr = (int*)ws;   ws += (size_t)(NN + 1) * 4;
  int*   cursor  = (int*)ws;   ws += (size_t)NN * 4;
  int*   col     = (int*)ws;   ws += (size_t)EE * 4;

  // zero the accumulated buffers (sums + counts are adjacent)
  hipMemsetAsync(sums, 0, (128 + NN) * sizeof(int), stream);

  gemm_al_kernel<<<NN / 16, 256, 0, stream>>>(x, W, Wres, a_src, a_dst, h, resb, al_s, al_d);
  hist_kernel<<<(EE + 255) / 256, 256, 0, stream>>>(ei + EE, counts);
  scan_kernel<<<1, 1024, 0, stream>>>(counts, row_ptr, cursor);
  scatter_kernel<<<(EE + 255) / 256, 256, 0, stream>>>(ei, ei + EE, cursor, col);
  node_kernel<<<NN / 4, 256, 0, stream>>>(h, al_s, al_d, row_ptr, col, out_pre);
  stats_kernel<<<256, 256, 0, stream>>>(out_pre, sums);
  final_kernel<<<NN * HC / 256, 256, 0, stream>>>(out_pre, resb, sums, gamma, beta, out);
}

// Round 2
// 257.431 us; speedup vs baseline: 1.3142x; 1.3142x over previous
//
#include <hip/hip_runtime.h>
#include <hip/hip_bf16.h>

#define NN 50000
#define EE 800000
#define IN_F 128
#define HC 64
#define NEG_SLOPE 0.2f
#define BN_EPS 1e-5f
#define SCAN_NB ((NN + 1023) / 1024)   // 49 blocks of 1024 elements

// ---------------- Kernel 1: h = x@W, res = x@W_res, al_s, al_d ----------------
// block = 256 threads, 16 rows/block. thread -> (row r = tid>>4, channels c4 = (tid&15)*4 .. +3)
__global__ __launch_bounds__(256) void gemm_al_kernel(
    const float* __restrict__ x, const float* __restrict__ W, const float* __restrict__ Wres,
    const float* __restrict__ a_src, const float* __restrict__ a_dst,
    float* __restrict__ h, float* __restrict__ res,
    float* __restrict__ al_s, float* __restrict__ al_d) {
  __shared__ float W_lds[IN_F * HC];    // 32KB, layout [k][c]
  __shared__ float Wr_lds[IN_F * HC];   // 32KB
  __shared__ float x_lds[16 * 132];     // 16 rows, stride 132 (bank-conflict-free broadcast)

  const int tid = threadIdx.x;
  for (int i = tid; i < IN_F * HC / 4; i += 256) {
    ((float4*)W_lds)[i]  = ((const float4*)W)[i];
    ((float4*)Wr_lds)[i] = ((const float4*)Wres)[i];
  }
  const int r0 = blockIdx.x * 16;
  for (int i = tid; i < 512; i += 256) {
    int row = i >> 5;
    int kk = i & 31;
    *(float4*)&x_lds[row * 132 + kk * 4] = ((const float4*)(x + (size_t)r0 * IN_F))[i];
  }
  __syncthreads();

  const int r = tid >> 4;
  const int c4 = (tid & 15) * 4;
  float4 acc1 = make_float4(0.f, 0.f, 0.f, 0.f);
  float4 acc2 = make_float4(0.f, 0.f, 0.f, 0.f);
#pragma unroll 8
  for (int k = 0; k < IN_F; ++k) {
    float xv = x_lds[r * 132 + k];
    float4 w  = *(const float4*)&W_lds[k * HC + c4];
    float4 wr = *(const float4*)&Wr_lds[k * HC + c4];
    acc1.x = fmaf(xv, w.x, acc1.x);
    acc1.y = fmaf(xv, w.y, acc1.y);
    acc1.z = fmaf(xv, w.z, acc1.z);
    acc1.w = fmaf(xv, w.w, acc1.w);
    acc2.x = fmaf(xv, wr.x, acc2.x);
    acc2.y = fmaf(xv, wr.y, acc2.y);
    acc2.z = fmaf(xv, wr.z, acc2.z);
    acc2.w = fmaf(xv, wr.w, acc2.w);
  }
  const int node = r0 + r;
  *(float4*)&h[(size_t)node * HC + c4]   = acc1;
  *(float4*)&res[(size_t)node * HC + c4] = acc2;

  const int head = (tid & 15) >> 2;
  const int coff = c4 & 15;
  float4 as4 = *(const float4*)&a_src[head * 16 + coff];
  float4 ad4 = *(const float4*)&a_dst[head * 16 + coff];
  float als = acc1.x * as4.x + acc1.y * as4.y + acc1.z * as4.z + acc1.w * as4.w;
  float ald = acc1.x * ad4.x + acc1.y * ad4.y + acc1.z * ad4.z + acc1.w * ad4.w;
  als += __shfl_xor(als, 1); als += __shfl_xor(als, 2);
  ald += __shfl_xor(ald, 1); ald += __shfl_xor(ald, 2);
  if ((tid & 3) == 0) {
    al_s[node * 4 + head] = als;
    al_d[node * 4 + head] = ald;
  }
}

// ---------------- Kernel 2: histogram of dst ----------------
__global__ __launch_bounds__(256) void hist_kernel(const int* __restrict__ dst,
                                                   int* __restrict__ counts) {
  int e = blockIdx.x * 256 + threadIdx.x;
  if (e < EE) atomicAdd(&counts[dst[e]], 1);
}

// ---------------- Kernel 3a: per-block scan (49 blocks, 1024 elems each) ----------------
__global__ __launch_bounds__(256) void scan1_kernel(const int* __restrict__ counts,
                                                    int* __restrict__ row_ptr,
                                                    int* __restrict__ blk_sums) {
  const int tid = threadIdx.x;
  const int base = blockIdx.x * 1024 + tid * 4;
  int4 v = make_int4(0, 0, 0, 0);
  if (base + 3 < NN) {
    v = *(const int4*)&counts[base];
  } else {
    if (base + 0 < NN) v.x = counts[base + 0];
    if (base + 1 < NN) v.y = counts[base + 1];
    if (base + 2 < NN) v.z = counts[base + 2];
    if (base + 3 < NN) v.w = counts[base + 3];
  }
  const int s = v.x + v.y + v.z + v.w;
  const int lane = tid & 63;
  const int wave = tid >> 6;
  int incl = s;
#pragma unroll
  for (int off = 1; off < 64; off <<= 1) {
    int t = __shfl_up(incl, off);
    if (lane >= off) incl += t;
  }
  __shared__ int wsum[4];
  if (lane == 63) wsum[wave] = incl;
  __syncthreads();
  int woff = 0;
  for (int w = 0; w < wave; ++w) woff += wsum[w];
  const int excl = woff + incl - s;   // exclusive prefix of this thread's first element
  int4 o;
  o.x = excl;
  o.y = o.x + v.x;
  o.z = o.y + v.y;
  o.w = o.z + v.z;
  if (base + 3 < NN) {
    *(int4*)&row_ptr[base] = o;
  } else {
    if (base + 0 < NN) row_ptr[base + 0] = o.x;
    if (base + 1 < NN) row_ptr[base + 1] = o.y;
    if (base + 2 < NN) row_ptr[base + 2] = o.z;
    if (base + 3 < NN) row_ptr[base + 3] = o.w;
  }
  if (tid == 255) blk_sums[blockIdx.x] = woff + incl;   // block total
}

// ---------------- Kernel 3b: scan of 49 block sums (single wave) ----------------
__global__ __launch_bounds__(64) void scan2_kernel(int* __restrict__ blk_sums,
                                                   int* __restrict__ row_ptr) {
  const int lane = threadIdx.x;
  int v = (lane < SCAN_NB) ? blk_sums[lane] : 0;
  int incl = v;
#pragma unroll
  for (int off = 1; off < 64; off <<= 1) {
    int t = __shfl_up(incl, off);
    if (lane >= off) incl += t;
  }
  if (lane < SCAN_NB) blk_sums[lane] = incl - v;   // exclusive block offset
  if (lane == 63) row_ptr[NN] = incl;              // grand total (== EE)
}

// ---------------- Kernel 3c: add block offsets, fill cursor ----------------
__global__ __launch_bounds__(256) void scan3_kernel(int* __restrict__ row_ptr,
                                                    int* __restrict__ cursor,
                                                    const int* __restrict__ blk_sums) {
  int i = blockIdx.x * 256 + threadIdx.x;
  if (i < NN) {
    int e = row_ptr[i] + blk_sums[i >> 10];
    row_ptr[i] = e;
    cursor[i] = e;
  }
}

// ---------------- Kernel 4: scatter edges into CSR ----------------
__global__ __launch_bounds__(256) void scatter_kernel(const int* __restrict__ src,
                                                      const int* __restrict__ dst,
                                                      int* __restrict__ cursor,
                                                      int* __restrict__ col) {
  int e = blockIdx.x * 256 + threadIdx.x;
  if (e < EE) {
    int d = dst[e];
    int p = atomicAdd(&cursor[d], 1);
    col[p] = src[e];
  }
}

// ---------------- Kernel 5: per-node attention aggregate (wave per node) ----------------
__global__ __launch_bounds__(256) void node_kernel(
    const float* __restrict__ h, const float* __restrict__ al_s, const float* __restrict__ al_d,
    const int* __restrict__ row_ptr, const int* __restrict__ col,
    float* __restrict__ out_pre) {
  const int node = blockIdx.x * 4 + (threadIdx.x >> 6);
  const int lane = threadIdx.x & 63;
  const int head = lane >> 4;

  const float ald = al_d[node * 4 + head];
  float e0 = al_s[node * 4 + head] + ald;
  e0 = e0 > 0.f ? e0 : NEG_SLOPE * e0;
  float m = __expf(e0);
  float denom = m;
  float acc = m * h[(size_t)node * HC + lane];

  const int beg = row_ptr[node];
  const int end = row_ptr[node + 1];
  for (int idx = beg; idx < end; ++idx) {
    int s = col[idx];
    float as = al_s[s * 4 + head];
    float ee = as + ald;
    ee = ee > 0.f ? ee : NEG_SLOPE * ee;
    float mm = __expf(ee);
    denom += mm;
    acc = fmaf(mm, h[(size_t)s * HC + lane], acc);
  }
  out_pre[(size_t)node * HC + lane] = acc / denom;
}

// ---------------- Kernel 6: BN statistics (sum, sumsq per channel) ----------------
__global__ __launch_bounds__(256) void stats_kernel(const float* __restrict__ out_pre,
                                                    float* __restrict__ sums) {
  const int c = threadIdx.x & 63;
  const int rg = threadIdx.x >> 6;
  float s = 0.f, s2 = 0.f;
  for (int r = blockIdx.x * 4 + rg; r < NN; r += gridDim.x * 4) {
    float v = out_pre[(size_t)r * HC + c];
    s += v;
    s2 = fmaf(v, v, s2);
  }
  __shared__ float lds[512];
  lds[threadIdx.x] = s;
  lds[256 + threadIdx.x] = s2;
  __syncthreads();
  if (threadIdx.x < 64) {
    float ts = lds[c] + lds[64 + c] + lds[128 + c] + lds[192 + c];
    float t2 = lds[256 + c] + lds[256 + 64 + c] + lds[256 + 128 + c] + lds[256 + 192 + c];
    atomicAdd(&sums[c], ts);
    atomicAdd(&sums[64 + c], t2);
  }
}

// ---------------- Kernel 7: BN + ELU + residual ----------------
__global__ __launch_bounds__(256) void final_kernel(
    const float* __restrict__ out_pre, const float* __restrict__ res,
    const float* __restrict__ sums, const float* __restrict__ gamma,
    const float* __restrict__ beta, float* __restrict__ out) {
  const int i = blockIdx.x * 256 + threadIdx.x;
  const int c = i & 63;
  const float inv_n = 1.0f / (float)NN;
  float mu = sums[c] * inv_n;
  float var = sums[64 + c] * inv_n - mu * mu;
  float rinv = rsqrtf(var + BN_EPS);
  float v = (out_pre[i] - mu) * rinv * gamma[c] + beta[c];
  v = v > 0.f ? v : (__expf(v) - 1.0f);
  out[i] = v + res[i];
}

extern "C" void kernel_launch(void* const* d_in, const int* in_sizes, int n_in,
                              void* d_out, int out_size, void* d_ws, size_t ws_size,
                              hipStream_t stream) {
  const float* x     = (const float*)d_in[0];
  const int*   ei    = (const int*)d_in[1];     // [2,E]: src = ei, dst = ei+E
  const float* W     = (const float*)d_in[2];
  const float* a_src = (const float*)d_in[3];
  const float* a_dst = (const float*)d_in[4];
  // d_in[5] = bias: cancels exactly through BatchNorm mean-subtraction -> unused
  const float* gamma = (const float*)d_in[6];
  const float* beta  = (const float*)d_in[7];
  const float* Wres  = (const float*)d_in[8];
  float* out = (float*)d_out;

  char* ws = (char*)d_ws;
  float* h        = (float*)ws; ws += (size_t)NN * HC * 4;
  float* resb     = (float*)ws; ws += (size_t)NN * HC * 4;
  float* out_pre  = (float*)ws; ws += (size_t)NN * HC * 4;
  float* al_s     = (float*)ws; ws += (size_t)NN * 4 * 4;
  float* al_d     = (float*)ws; ws += (size_t)NN * 4 * 4;
  float* sums     = (float*)ws; ws += 128 * 4;          // [0:64]=sum, [64:128]=sumsq
  int*   counts   = (int*)ws;   ws += (size_t)NN * 4;   // contiguous with sums: one memset
  int*   row_ptr  = (int*)ws;   ws += (size_t)(NN + 1) * 4;
  int*   cursor   = (int*)ws;   ws += (size_t)NN * 4;
  int*   blk_sums = (int*)ws;   ws += 64 * 4;
  int*   col      = (int*)ws;   ws += (size_t)EE * 4;

  hipMemsetAsync(sums, 0, (128 + NN) * sizeof(int), stream);

  gemm_al_kernel<<<NN / 16, 256, 0, stream>>>(x, W, Wres, a_src, a_dst, h, resb, al_s, al_d);
  hist_kernel<<<(EE + 255) / 256, 256, 0, stream>>>(ei + EE, counts);
  scan1_kernel<<<SCAN_NB, 256, 0, stream>>>(counts, row_ptr, blk_sums);
  scan2_kernel<<<1, 64, 0, stream>>>(blk_sums, row_ptr);
  scan3_kernel<<<(NN + 255) / 256, 256, 0, stream>>>(row_ptr, cursor, blk_sums);
  scatter_kernel<<<(EE + 255) / 256, 256, 0, stream>>>(ei, ei + EE, cursor, col);
  node_kernel<<<NN / 4, 256, 0, stream>>>(h, al_s, al_d, row_ptr, col, out_pre);
  stats_kernel<<<256, 256, 0, stream>>>(out_pre, sums);
  final_kernel<<<NN * HC / 256, 256, 0, stream>>>(out_pre, resb, sums, gamma, beta, out);
}

// Round 3
// 209.157 us; speedup vs baseline: 1.6176x; 1.2308x over previous
//
#include <hip/hip_runtime.h>
#include <hip/hip_bf16.h>

#define NN 50000
#define EE 800000
#define IN_F 128
#define HC 64
#define NEG_SLOPE 0.2f
#define BN_EPS 1e-5f
#define SCAN_NB ((NN + 1023) / 1024)   // 49 blocks of 1024 elements

// ---------------- Kernel 1: h = x@W, res = x@W_res, al_s, al_d ----------------
__global__ __launch_bounds__(256) void gemm_al_kernel(
    const float* __restrict__ x, const float* __restrict__ W, const float* __restrict__ Wres,
    const float* __restrict__ a_src, const float* __restrict__ a_dst,
    float* __restrict__ h, float* __restrict__ res,
    float* __restrict__ al_s, float* __restrict__ al_d) {
  __shared__ float W_lds[IN_F * HC];    // 32KB, layout [k][c]
  __shared__ float Wr_lds[IN_F * HC];   // 32KB
  __shared__ float x_lds[16 * 132];

  const int tid = threadIdx.x;
  for (int i = tid; i < IN_F * HC / 4; i += 256) {
    ((float4*)W_lds)[i]  = ((const float4*)W)[i];
    ((float4*)Wr_lds)[i] = ((const float4*)Wres)[i];
  }
  const int r0 = blockIdx.x * 16;
  for (int i = tid; i < 512; i += 256) {
    int row = i >> 5;
    int kk = i & 31;
    *(float4*)&x_lds[row * 132 + kk * 4] = ((const float4*)(x + (size_t)r0 * IN_F))[i];
  }
  __syncthreads();

  const int r = tid >> 4;
  const int c4 = (tid & 15) * 4;
  float4 acc1 = make_float4(0.f, 0.f, 0.f, 0.f);
  float4 acc2 = make_float4(0.f, 0.f, 0.f, 0.f);
#pragma unroll 8
  for (int k = 0; k < IN_F; ++k) {
    float xv = x_lds[r * 132 + k];
    float4 w  = *(const float4*)&W_lds[k * HC + c4];
    float4 wr = *(const float4*)&Wr_lds[k * HC + c4];
    acc1.x = fmaf(xv, w.x, acc1.x);
    acc1.y = fmaf(xv, w.y, acc1.y);
    acc1.z = fmaf(xv, w.z, acc1.z);
    acc1.w = fmaf(xv, w.w, acc1.w);
    acc2.x = fmaf(xv, wr.x, acc2.x);
    acc2.y = fmaf(xv, wr.y, acc2.y);
    acc2.z = fmaf(xv, wr.z, acc2.z);
    acc2.w = fmaf(xv, wr.w, acc2.w);
  }
  const int node = r0 + r;
  *(float4*)&h[(size_t)node * HC + c4]   = acc1;
  *(float4*)&res[(size_t)node * HC + c4] = acc2;

  const int head = (tid & 15) >> 2;
  const int coff = c4 & 15;
  float4 as4 = *(const float4*)&a_src[head * 16 + coff];
  float4 ad4 = *(const float4*)&a_dst[head * 16 + coff];
  float als = acc1.x * as4.x + acc1.y * as4.y + acc1.z * as4.z + acc1.w * as4.w;
  float ald = acc1.x * ad4.x + acc1.y * ad4.y + acc1.z * ad4.z + acc1.w * ad4.w;
  als += __shfl_xor(als, 1); als += __shfl_xor(als, 2);
  ald += __shfl_xor(ald, 1); ald += __shfl_xor(ald, 2);
  if ((tid & 3) == 0) {
    al_s[node * 4 + head] = als;
    al_d[node * 4 + head] = ald;
  }
}

// ---------------- Kernel 2: histogram of dst ----------------
__global__ __launch_bounds__(256) void hist_kernel(const int* __restrict__ dst,
                                                   int* __restrict__ counts) {
  int e = blockIdx.x * 256 + threadIdx.x;
  if (e < EE) atomicAdd(&counts[dst[e]], 1);
}

// ---------------- Kernel 3a: per-block scan ----------------
__global__ __launch_bounds__(256) void scan1_kernel(const int* __restrict__ counts,
                                                    int* __restrict__ row_ptr,
                                                    int* __restrict__ blk_sums) {
  const int tid = threadIdx.x;
  const int base = blockIdx.x * 1024 + tid * 4;
  int4 v = make_int4(0, 0, 0, 0);
  if (base + 3 < NN) {
    v = *(const int4*)&counts[base];
  } else {
    if (base + 0 < NN) v.x = counts[base + 0];
    if (base + 1 < NN) v.y = counts[base + 1];
    if (base + 2 < NN) v.z = counts[base + 2];
    if (base + 3 < NN) v.w = counts[base + 3];
  }
  const int s = v.x + v.y + v.z + v.w;
  const int lane = tid & 63;
  const int wave = tid >> 6;
  int incl = s;
#pragma unroll
  for (int off = 1; off < 64; off <<= 1) {
    int t = __shfl_up(incl, off);
    if (lane >= off) incl += t;
  }
  __shared__ int wsum[4];
  if (lane == 63) wsum[wave] = incl;
  __syncthreads();
  int woff = 0;
  for (int w = 0; w < wave; ++w) woff += wsum[w];
  const int excl = woff + incl - s;
  int4 o;
  o.x = excl;
  o.y = o.x + v.x;
  o.z = o.y + v.y;
  o.w = o.z + v.z;
  if (base + 3 < NN) {
    *(int4*)&row_ptr[base] = o;
  } else {
    if (base + 0 < NN) row_ptr[base + 0] = o.x;
    if (base + 1 < NN) row_ptr[base + 1] = o.y;
    if (base + 2 < NN) row_ptr[base + 2] = o.z;
    if (base + 3 < NN) row_ptr[base + 3] = o.w;
  }
  if (tid == 255) blk_sums[blockIdx.x] = woff + incl;
}

// ---------------- Kernel 3b: scan of block sums (single wave) ----------------
__global__ __launch_bounds__(64) void scan2_kernel(int* __restrict__ blk_sums,
                                                   int* __restrict__ row_ptr) {
  const int lane = threadIdx.x;
  int v = (lane < SCAN_NB) ? blk_sums[lane] : 0;
  int incl = v;
#pragma unroll
  for (int off = 1; off < 64; off <<= 1) {
    int t = __shfl_up(incl, off);
    if (lane >= off) incl += t;
  }
  if (lane < SCAN_NB) blk_sums[lane] = incl - v;
  if (lane == 63) row_ptr[NN] = incl;
}

// ---------------- Kernel 3c: add block offsets, fill cursor ----------------
__global__ __launch_bounds__(256) void scan3_kernel(int* __restrict__ row_ptr,
                                                    int* __restrict__ cursor,
                                                    const int* __restrict__ blk_sums) {
  int i = blockIdx.x * 256 + threadIdx.x;
  if (i < NN) {
    int e = row_ptr[i] + blk_sums[i >> 10];
    row_ptr[i] = e;
    cursor[i] = e;
  }
}

// ---------------- Kernel 4: scatter edges into CSR + per-edge softmax numerators ----------
// Edge-parallel: latency of the al gathers + exp is hidden by 800K-thread TLP.
__global__ __launch_bounds__(256) void scatter_kernel(
    const int* __restrict__ src, const int* __restrict__ dst,
    const float* __restrict__ al_s, const float* __restrict__ al_d,
    int* __restrict__ cursor, int* __restrict__ col, float* __restrict__ mvals) {
  int e = blockIdx.x * 256 + threadIdx.x;
  if (e < EE) {
    int sn = src[e];
    int d = dst[e];
    float4 as = *(const float4*)&al_s[(size_t)sn * 4];
    float4 ad = *(const float4*)&al_d[(size_t)d * 4];
    float4 mv;
    float t;
    t = as.x + ad.x; t = t > 0.f ? t : NEG_SLOPE * t; mv.x = __expf(t);
    t = as.y + ad.y; t = t > 0.f ? t : NEG_SLOPE * t; mv.y = __expf(t);
    t = as.z + ad.z; t = t > 0.f ? t : NEG_SLOPE * t; mv.z = __expf(t);
    t = as.w + ad.w; t = t > 0.f ? t : NEG_SLOPE * t; mv.w = __expf(t);
    int p = atomicAdd(&cursor[d], 1);
    col[p] = sn;
    *(float4*)&mvals[(size_t)p * 4] = mv;
  }
}

// ---------------- Kernel 5: per-node aggregate (wave per node, 1 dependent gather) ------
__global__ __launch_bounds__(256) void node_kernel(
    const float* __restrict__ h, const float* __restrict__ al_s, const float* __restrict__ al_d,
    const int* __restrict__ row_ptr, const int* __restrict__ col,
    const float* __restrict__ mvals, float* __restrict__ out_pre) {
  const int node = blockIdx.x * 4 + (threadIdx.x >> 6);
  const int lane = threadIdx.x & 63;
  const int head = lane >> 4;

  const float ald = al_d[node * 4 + head];
  float e0 = al_s[node * 4 + head] + ald;   // self loop
  e0 = e0 > 0.f ? e0 : NEG_SLOPE * e0;
  float m = __expf(e0);
  float denom = m;
  float acc = m * h[(size_t)node * HC + lane];

  const int beg = row_ptr[node];
  const int end = row_ptr[node + 1];
  int idx = beg;
  // unroll x8: col/mvals addresses depend only on idx -> 16 loads issue immediately,
  // then 8 independent h-gathers in flight. Single dependent level.
  for (; idx + 8 <= end; idx += 8) {
    int s[8];
    float mm[8];
#pragma unroll
    for (int u = 0; u < 8; ++u) s[u] = col[idx + u];
#pragma unroll
    for (int u = 0; u < 8; ++u) mm[u] = mvals[(size_t)(idx + u) * 4 + head];
#pragma unroll
    for (int u = 0; u < 8; ++u) {
      denom += mm[u];
      acc = fmaf(mm[u], h[(size_t)s[u] * HC + lane], acc);
    }
  }
  for (; idx < end; ++idx) {
    int s = col[idx];
    float mm = mvals[(size_t)idx * 4 + head];
    denom += mm;
    acc = fmaf(mm, h[(size_t)s * HC + lane], acc);
  }
  out_pre[(size_t)node * HC + lane] = acc / denom;
}

// ---------------- Kernel 6: BN statistics ----------------
__global__ __launch_bounds__(256) void stats_kernel(const float* __restrict__ out_pre,
                                                    float* __restrict__ sums) {
  const int c = threadIdx.x & 63;
  const int rg = threadIdx.x >> 6;
  float s = 0.f, s2 = 0.f;
  for (int r = blockIdx.x * 4 + rg; r < NN; r += gridDim.x * 4) {
    float v = out_pre[(size_t)r * HC + c];
    s += v;
    s2 = fmaf(v, v, s2);
  }
  __shared__ float lds[512];
  lds[threadIdx.x] = s;
  lds[256 + threadIdx.x] = s2;
  __syncthreads();
  if (threadIdx.x < 64) {
    float ts = lds[c] + lds[64 + c] + lds[128 + c] + lds[192 + c];
    float t2 = lds[256 + c] + lds[256 + 64 + c] + lds[256 + 128 + c] + lds[256 + 192 + c];
    atomicAdd(&sums[c], ts);
    atomicAdd(&sums[64 + c], t2);
  }
}

// ---------------- Kernel 7: BN + ELU + residual ----------------
__global__ __launch_bounds__(256) void final_kernel(
    const float* __restrict__ out_pre, const float* __restrict__ res,
    const float* __restrict__ sums, const float* __restrict__ gamma,
    const float* __restrict__ beta, float* __restrict__ out) {
  const int i = blockIdx.x * 256 + threadIdx.x;
  const int c = i & 63;
  const float inv_n = 1.0f / (float)NN;
  float mu = sums[c] * inv_n;
  float var = sums[64 + c] * inv_n - mu * mu;
  float rinv = rsqrtf(var + BN_EPS);
  float v = (out_pre[i] - mu) * rinv * gamma[c] + beta[c];
  v = v > 0.f ? v : (__expf(v) - 1.0f);
  out[i] = v + res[i];
}

extern "C" void kernel_launch(void* const* d_in, const int* in_sizes, int n_in,
                              void* d_out, int out_size, void* d_ws, size_t ws_size,
                              hipStream_t stream) {
  const float* x     = (const float*)d_in[0];
  const int*   ei    = (const int*)d_in[1];     // [2,E]: src = ei, dst = ei+E
  const float* W     = (const float*)d_in[2];
  const float* a_src = (const float*)d_in[3];
  const float* a_dst = (const float*)d_in[4];
  // d_in[5] = bias: cancels exactly through BatchNorm mean-subtraction -> unused
  const float* gamma = (const float*)d_in[6];
  const float* beta  = (const float*)d_in[7];
  const float* Wres  = (const float*)d_in[8];
  float* out = (float*)d_out;

  char* ws = (char*)d_ws;
  float* h        = (float*)ws; ws += (size_t)NN * HC * 4;
  float* resb     = (float*)ws; ws += (size_t)NN * HC * 4;
  float* out_pre  = (float*)ws; ws += (size_t)NN * HC * 4;
  float* al_s     = (float*)ws; ws += (size_t)NN * 4 * 4;
  float* al_d     = (float*)ws; ws += (size_t)NN * 4 * 4;
  float* mvals    = (float*)ws; ws += (size_t)EE * 4 * 4;   // 16B-aligned; [E][4] heads, CSR order
  float* sums     = (float*)ws; ws += 128 * 4;              // [0:64]=sum, [64:128]=sumsq
  int*   counts   = (int*)ws;   ws += (size_t)NN * 4;       // contiguous with sums: one memset
  int*   row_ptr  = (int*)ws;   ws += (size_t)(NN + 1) * 4;
  int*   cursor   = (int*)ws;   ws += (size_t)NN * 4;
  int*   blk_sums = (int*)ws;   ws += 64 * 4;
  int*   col      = (int*)ws;   ws += (size_t)EE * 4;

  hipMemsetAsync(sums, 0, (128 + NN) * sizeof(int), stream);

  gemm_al_kernel<<<NN / 16, 256, 0, stream>>>(x, W, Wres, a_src, a_dst, h, resb, al_s, al_d);
  hist_kernel<<<(EE + 255) / 256, 256, 0, stream>>>(ei + EE, counts);
  scan1_kernel<<<SCAN_NB, 256, 0, stream>>>(counts, row_ptr, blk_sums);
  scan2_kernel<<<1, 64, 0, stream>>>(blk_sums, row_ptr);
  scan3_kernel<<<(NN + 255) / 256, 256, 0, stream>>>(row_ptr, cursor, blk_sums);
  scatter_kernel<<<(EE + 255) / 256, 256, 0, stream>>>(ei, ei + EE, al_s, al_d, cursor, col, mvals);
  node_kernel<<<NN / 4, 256, 0, stream>>>(h, al_s, al_d, row_ptr, col, mvals, out_pre);
  stats_kernel<<<256, 256, 0, stream>>>(out_pre, sums);
  final_kernel<<<NN * HC / 256, 256, 0, stream>>>(out_pre, resb, sums, gamma, beta, out);
}

// Round 4
// 182.575 us; speedup vs baseline: 1.8531x; 1.1456x over previous
//
#include <hip/hip_runtime.h>
#include <hip/hip_bf16.h>

#define NN 50000
#define EE 800000
#define IN_F 128
#define HC 64
#define NEG_SLOPE 0.2f
#define BN_EPS 1e-5f
#define SCAN_NB ((NN + 1023) / 1024)   // 49 blocks of 1024 elements

typedef __attribute__((ext_vector_type(8))) short short8;
typedef __attribute__((ext_vector_type(4))) float f32x4;

__device__ __forceinline__ ushort f2bf(float f) {
  uint u = __float_as_uint(f);
  uint r = u + 0x7FFF + ((u >> 16) & 1);   // RNE
  return (ushort)(r >> 16);
}
__device__ __forceinline__ float bf2f(ushort u) {
  return __uint_as_float(((uint)u) << 16);
}

// ---------------- Kernel 1: MFMA bf16 GEMM: h=x@W (bf16 out), res=x@Wres (f32), al_s, al_d --
// 256 threads = 4 waves. Block: 64 rows x 128 cols (cols 0-63 = W, 64-127 = Wres).
// Wave w: rows r0+w*16..+15, all 8 col-tiles, K=128 in 4 MFMA steps.
// LDS: B [128col][128k] bf16 + x [64row][128k] bf16, both XOR-swizzled (T2) so
// frag ds_read_b128 is 2-way (free) instead of 16-way bank conflict.
__global__ __launch_bounds__(256) void gemm_mfma_kernel(
    const float* __restrict__ x, const float* __restrict__ W, const float* __restrict__ Wres,
    const float* __restrict__ a_src, const float* __restrict__ a_dst,
    ushort* __restrict__ h, float* __restrict__ res,
    float* __restrict__ al_s, float* __restrict__ al_d) {
  __shared__ ushort bs[128 * 128];   // [col][k] bf16, swizzled: byte ^= (col&7)<<4
  __shared__ ushort xs[64 * 128];    // [row][k] bf16, swizzled: byte ^= (row&7)<<4

  const int tid = threadIdx.x;
  const int r0 = blockIdx.x * 64;

  // ---- stage B = [W | Wres] transposed to [col][k], bf16, swizzled
  {
    const int c4 = (tid & 31) * 4;          // 0..124
    const int kb = (tid >> 5) * 16;         // 0..112
    const float* src0 = (c4 < HC) ? (W + c4) : (Wres + (c4 - HC));
    char* base = (char*)bs;
#pragma unroll
    for (int j = 0; j < 8; ++j) {
      int k0 = kb + j * 2;
      float4 fa = *(const float4*)(src0 + (size_t)k0 * HC);
      float4 fb = *(const float4*)(src0 + (size_t)(k0 + 1) * HC);
      uint p0 = (uint)f2bf(fa.x) | ((uint)f2bf(fb.x) << 16);
      uint p1 = (uint)f2bf(fa.y) | ((uint)f2bf(fb.y) << 16);
      uint p2 = (uint)f2bf(fa.z) | ((uint)f2bf(fb.z) << 16);
      uint p3 = (uint)f2bf(fa.w) | ((uint)f2bf(fb.w) << 16);
      *(uint*)(base + (((c4 + 0) * 256 + k0 * 2) ^ (((c4 + 0) & 7) << 4))) = p0;
      *(uint*)(base + (((c4 + 1) * 256 + k0 * 2) ^ (((c4 + 1) & 7) << 4))) = p1;
      *(uint*)(base + (((c4 + 2) * 256 + k0 * 2) ^ (((c4 + 2) & 7) << 4))) = p2;
      *(uint*)(base + (((c4 + 3) * 256 + k0 * 2) ^ (((c4 + 3) & 7) << 4))) = p3;
    }
  }
  // ---- stage x tile [64][128] bf16, swizzled (coalesced float4 global reads)
  {
    char* base = (char*)xs;
#pragma unroll
    for (int i = 0; i < 8; ++i) {
      int f4 = i * 256 + tid;          // float4 id in 64x128 tile
      int row = f4 >> 5;
      int kq = (f4 & 31) * 4;
      int gr = r0 + row;
      float4 v = make_float4(0.f, 0.f, 0.f, 0.f);
      if (gr < NN) v = *(const float4*)(x + (size_t)gr * IN_F + kq);
      uint lo = (uint)f2bf(v.x) | ((uint)f2bf(v.y) << 16);
      uint hi = (uint)f2bf(v.z) | ((uint)f2bf(v.w) << 16);
      uint off = (uint)((row * 256 + kq * 2) ^ ((row & 7) << 4));
      *(uint2*)(base + off) = make_uint2(lo, hi);   // 8B chunk stays inside one 16B unit
    }
  }
  __syncthreads();

  const int w = tid >> 6;
  const int l = tid & 63;
  const int lr = l & 15;         // row-in-tile (A) / col-in-tile (B/D)
  const int lk = (l >> 4) * 8;   // k subgroup base

  f32x4 acc[8];
#pragma unroll
  for (int i = 0; i < 8; ++i) acc[i] = (f32x4){0.f, 0.f, 0.f, 0.f};

  const char* xb = (const char*)xs;
  const char* bb = (const char*)bs;
  const int arow = w * 16 + lr;
#pragma unroll
  for (int ks = 0; ks < 4; ++ks) {
    const int kbase = ks * 32 + lk;
    short8 af = *(const short8*)(xb + ((arow * 256 + kbase * 2) ^ ((arow & 7) << 4)));
#pragma unroll
    for (int ct = 0; ct < 8; ++ct) {
      const int c = ct * 16 + lr;
      short8 bfr = *(const short8*)(bb + ((c * 256 + kbase * 2) ^ ((c & 7) << 4)));
      acc[ct] = __builtin_amdgcn_mfma_f32_16x16x32_bf16(af, bfr, acc[ct], 0, 0, 0);
    }
  }

  // ---- epilogue: stores (D layout: col=lane&15, row=(lane>>4)*4+reg)
  const int rb = r0 + w * 16;
#pragma unroll
  for (int ct = 0; ct < 8; ++ct) {
#pragma unroll
    for (int r = 0; r < 4; ++r) {
      int gr = rb + (l >> 4) * 4 + r;
      if (gr < NN) {
        if (ct < 4) h[(size_t)gr * HC + ct * 16 + lr] = f2bf(acc[ct][r]);
        else        res[(size_t)gr * HC + (ct - 4) * 16 + lr] = acc[ct][r];
      }
    }
  }

  // ---- al_s/al_d from accumulators (heads = col-tiles 0..3), 16-lane shuffle reduce
  float myS[4] = {0.f, 0.f, 0.f, 0.f};
  float myD[4] = {0.f, 0.f, 0.f, 0.f};
#pragma unroll
  for (int ct = 0; ct < 4; ++ct) {
    float asv = a_src[ct * 16 + lr];   // a_src[head][c], head=ct
    float adv = a_dst[ct * 16 + lr];
#pragma unroll
    for (int r = 0; r < 4; ++r) {
      float ps = acc[ct][r] * asv;
      float pd = acc[ct][r] * adv;
      ps += __shfl_xor(ps, 1); ps += __shfl_xor(ps, 2); ps += __shfl_xor(ps, 4); ps += __shfl_xor(ps, 8);
      pd += __shfl_xor(pd, 1); pd += __shfl_xor(pd, 2); pd += __shfl_xor(pd, 4); pd += __shfl_xor(pd, 8);
      if (lr == ct) { myS[r] = ps; myD[r] = pd; }
    }
  }
  if (lr < 4) {
#pragma unroll
    for (int r = 0; r < 4; ++r) {
      int gr = rb + (l >> 4) * 4 + r;
      if (gr < NN) {
        al_s[gr * 4 + lr] = myS[r];
        al_d[gr * 4 + lr] = myD[r];
      }
    }
  }
}

// ---------------- Kernel 2: histogram of dst ----------------
__global__ __launch_bounds__(256) void hist_kernel(const int* __restrict__ dst,
                                                   int* __restrict__ counts) {
  int e = blockIdx.x * 256 + threadIdx.x;
  if (e < EE) atomicAdd(&counts[dst[e]], 1);
}

// ---------------- Kernel 3a: per-block scan ----------------
__global__ __launch_bounds__(256) void scan1_kernel(const int* __restrict__ counts,
                                                    int* __restrict__ row_ptr,
                                                    int* __restrict__ blk_sums) {
  const int tid = threadIdx.x;
  const int base = blockIdx.x * 1024 + tid * 4;
  int4 v = make_int4(0, 0, 0, 0);
  if (base + 3 < NN) {
    v = *(const int4*)&counts[base];
  } else {
    if (base + 0 < NN) v.x = counts[base + 0];
    if (base + 1 < NN) v.y = counts[base + 1];
    if (base + 2 < NN) v.z = counts[base + 2];
    if (base + 3 < NN) v.w = counts[base + 3];
  }
  const int s = v.x + v.y + v.z + v.w;
  const int lane = tid & 63;
  const int wave = tid >> 6;
  int incl = s;
#pragma unroll
  for (int off = 1; off < 64; off <<= 1) {
    int t = __shfl_up(incl, off);
    if (lane >= off) incl += t;
  }
  __shared__ int wsum[4];
  if (lane == 63) wsum[wave] = incl;
  __syncthreads();
  int woff = 0;
  for (int w = 0; w < wave; ++w) woff += wsum[w];
  const int excl = woff + incl - s;
  int4 o;
  o.x = excl;
  o.y = o.x + v.x;
  o.z = o.y + v.y;
  o.w = o.z + v.z;
  if (base + 3 < NN) {
    *(int4*)&row_ptr[base] = o;
  } else {
    if (base + 0 < NN) row_ptr[base + 0] = o.x;
    if (base + 1 < NN) row_ptr[base + 1] = o.y;
    if (base + 2 < NN) row_ptr[base + 2] = o.z;
    if (base + 3 < NN) row_ptr[base + 3] = o.w;
  }
  if (tid == 255) blk_sums[blockIdx.x] = woff + incl;
}

// ---------------- Kernel 3b: scan of block sums (single wave) ----------------
__global__ __launch_bounds__(64) void scan2_kernel(int* __restrict__ blk_sums,
                                                   int* __restrict__ row_ptr) {
  const int lane = threadIdx.x;
  int v = (lane < SCAN_NB) ? blk_sums[lane] : 0;
  int incl = v;
#pragma unroll
  for (int off = 1; off < 64; off <<= 1) {
    int t = __shfl_up(incl, off);
    if (lane >= off) incl += t;
  }
  if (lane < SCAN_NB) blk_sums[lane] = incl - v;
  if (lane == 63) row_ptr[NN] = incl;
}

// ---------------- Kernel 3c: add block offsets, fill cursor ----------------
__global__ __launch_bounds__(256) void scan3_kernel(int* __restrict__ row_ptr,
                                                    int* __restrict__ cursor,
                                                    const int* __restrict__ blk_sums) {
  int i = blockIdx.x * 256 + threadIdx.x;
  if (i < NN) {
    int e = row_ptr[i] + blk_sums[i >> 10];
    row_ptr[i] = e;
    cursor[i] = e;
  }
}

// ---------------- Kernel 4: slim scatter: CSR col only (2 random touches/edge) ---------
__global__ __launch_bounds__(256) void scatter_kernel(const int* __restrict__ src,
                                                      const int* __restrict__ dst,
                                                      int* __restrict__ cursor,
                                                      int* __restrict__ col) {
  int e = blockIdx.x * 256 + threadIdx.x;
  if (e < EE) {
    int d = dst[e];
    int p = atomicAdd(&cursor[d], 1);
    col[p] = src[e];
  }
}

// ---------------- Kernel 5: per-node aggregate (wave per node) ----------------
// Per edge: col (seq) -> {al_s gather (1 line, L2-resident), h gather (1 line, bf16)}
// in parallel, x8 in flight; exp off the load chain.
__global__ __launch_bounds__(256) void node_kernel(
    const ushort* __restrict__ h, const float* __restrict__ al_s, const float* __restrict__ al_d,
    const int* __restrict__ row_ptr, const int* __restrict__ col,
    float* __restrict__ out_pre) {
  const int node = blockIdx.x * 4 + (threadIdx.x >> 6);
  const int lane = threadIdx.x & 63;
  const int head = lane >> 4;

  const float ald = al_d[node * 4 + head];
  float e0 = al_s[node * 4 + head] + ald;   // self loop
  e0 = e0 > 0.f ? e0 : NEG_SLOPE * e0;
  float m = __expf(e0);
  float denom = m;
  float acc = m * bf2f(h[(size_t)node * HC + lane]);

  const int beg = row_ptr[node];
  const int end = row_ptr[node + 1];
  int idx = beg;
  for (; idx + 8 <= end; idx += 8) {
    int s[8]; float as[8]; float hv[8];
#pragma unroll
    for (int u = 0; u < 8; ++u) s[u] = col[idx + u];
#pragma unroll
    for (int u = 0; u < 8; ++u) as[u] = al_s[s[u] * 4 + head];
#pragma unroll
    for (int u = 0; u < 8; ++u) hv[u] = bf2f(h[(size_t)s[u] * HC + lane]);
#pragma unroll
    for (int u = 0; u < 8; ++u) {
      float ee = as[u] + ald;
      ee = ee > 0.f ? ee : NEG_SLOPE * ee;
      float mm = __expf(ee);
      denom += mm;
      acc = fmaf(mm, hv[u], acc);
    }
  }
  for (; idx < end; ++idx) {
    int s = col[idx];
    float ee = al_s[s * 4 + head] + ald;
    ee = ee > 0.f ? ee : NEG_SLOPE * ee;
    float mm = __expf(ee);
    denom += mm;
    acc = fmaf(mm, bf2f(h[(size_t)s * HC + lane]), acc);
  }
  out_pre[(size_t)node * HC + lane] = acc / denom;
}

// ---------------- Kernel 6: BN statistics ----------------
__global__ __launch_bounds__(256) void stats_kernel(const float* __restrict__ out_pre,
                                                    float* __restrict__ sums) {
  const int c = threadIdx.x & 63;
  const int rg = threadIdx.x >> 6;
  float s = 0.f, s2 = 0.f;
  for (int r = blockIdx.x * 4 + rg; r < NN; r += gridDim.x * 4) {
    float v = out_pre[(size_t)r * HC + c];
    s += v;
    s2 = fmaf(v, v, s2);
  }
  __shared__ float lds[512];
  lds[threadIdx.x] = s;
  lds[256 + threadIdx.x] = s2;
  __syncthreads();
  if (threadIdx.x < 64) {
    float ts = lds[c] + lds[64 + c] + lds[128 + c] + lds[192 + c];
    float t2 = lds[256 + c] + lds[256 + 64 + c] + lds[256 + 128 + c] + lds[256 + 192 + c];
    atomicAdd(&sums[c], ts);
    atomicAdd(&sums[64 + c], t2);
  }
}

// ---------------- Kernel 7: BN + ELU + residual ----------------
__global__ __launch_bounds__(256) void final_kernel(
    const float* __restrict__ out_pre, const float* __restrict__ res,
    const float* __restrict__ sums, const float* __restrict__ gamma,
    const float* __restrict__ beta, float* __restrict__ out) {
  const int i = blockIdx.x * 256 + threadIdx.x;
  const int c = i & 63;
  const float inv_n = 1.0f / (float)NN;
  float mu = sums[c] * inv_n;
  float var = sums[64 + c] * inv_n - mu * mu;
  float rinv = rsqrtf(var + BN_EPS);
  float v = (out_pre[i] - mu) * rinv * gamma[c] + beta[c];
  v = v > 0.f ? v : (__expf(v) - 1.0f);
  out[i] = v + res[i];
}

extern "C" void kernel_launch(void* const* d_in, const int* in_sizes, int n_in,
                              void* d_out, int out_size, void* d_ws, size_t ws_size,
                              hipStream_t stream) {
  const float* x     = (const float*)d_in[0];
  const int*   ei    = (const int*)d_in[1];     // [2,E]: src = ei, dst = ei+E
  const float* W     = (const float*)d_in[2];
  const float* a_src = (const float*)d_in[3];
  const float* a_dst = (const float*)d_in[4];
  // d_in[5] = bias: cancels exactly through BatchNorm mean-subtraction -> unused
  const float* gamma = (const float*)d_in[6];
  const float* beta  = (const float*)d_in[7];
  const float* Wres  = (const float*)d_in[8];
  float* out = (float*)d_out;

  char* ws = (char*)d_ws;
  ushort* h       = (ushort*)ws; ws += (size_t)NN * HC * 2;   // bf16 h
  float* resb     = (float*)ws;  ws += (size_t)NN * HC * 4;
  float* out_pre  = (float*)ws;  ws += (size_t)NN * HC * 4;
  float* al_s     = (float*)ws;  ws += (size_t)NN * 4 * 4;
  float* al_d     = (float*)ws;  ws += (size_t)NN * 4 * 4;
  float* sums     = (float*)ws;  ws += 128 * 4;               // [0:64]=sum, [64:128]=sumsq
  int*   counts   = (int*)ws;    ws += (size_t)NN * 4;        // contiguous with sums: one memset
  int*   row_ptr  = (int*)ws;    ws += (size_t)(NN + 1) * 4;
  int*   cursor   = (int*)ws;    ws += (size_t)NN * 4;
  int*   blk_sums = (int*)ws;    ws += 64 * 4;
  int*   col      = (int*)ws;    ws += (size_t)EE * 4;

  hipMemsetAsync(sums, 0, (128 + NN) * sizeof(int), stream);

  gemm_mfma_kernel<<<(NN + 63) / 64, 256, 0, stream>>>(x, W, Wres, a_src, a_dst,
                                                       h, resb, al_s, al_d);
  hist_kernel<<<(EE + 255) / 256, 256, 0, stream>>>(ei + EE, counts);
  scan1_kernel<<<SCAN_NB, 256, 0, stream>>>(counts, row_ptr, blk_sums);
  scan2_kernel<<<1, 64, 0, stream>>>(blk_sums, row_ptr);
  scan3_kernel<<<(NN + 255) / 256, 256, 0, stream>>>(row_ptr, cursor, blk_sums);
  scatter_kernel<<<(EE + 255) / 256, 256, 0, stream>>>(ei, ei + EE, cursor, col);
  node_kernel<<<NN / 4, 256, 0, stream>>>(h, al_s, al_d, row_ptr, col, out_pre);
  stats_kernel<<<256, 256, 0, stream>>>(out_pre, sums);
  final_kernel<<<NN * HC / 256, 256, 0, stream>>>(out_pre, resb, sums, gamma, beta, out);
}